// Round 3
// baseline (478.411 us; speedup 1.0000x reference)
//
#include <hip/hip_runtime.h>
#include <hip/hip_bf16.h>

// Problem constants (fixed by the reference)
#define N_NODES 10000
#define N_EDGES 160000
#define ETOT    (N_NODES + N_EDGES)
#define DIM     1024
#define NHEAD   4
#define DHEAD   256
#define NGRAPH  64
#define NEG_SLOPE 0.2f

typedef short  bf16x8 __attribute__((ext_vector_type(8)));
typedef float  f32x4  __attribute__((ext_vector_type(4)));
typedef unsigned short u16x4 __attribute__((ext_vector_type(4)));

__device__ __forceinline__ unsigned short f2bf_rne(float v) {
    unsigned u = __builtin_bit_cast(unsigned, v);
    return (unsigned short)((u + 0x7fffu + ((u >> 16) & 1u)) >> 16);
}
__device__ __forceinline__ float bf2f(unsigned short b) {
    return __builtin_bit_cast(float, (unsigned)b << 16);
}
__device__ __forceinline__ float lrelu(float x) { return x > 0.f ? x : NEG_SLOPE * x; }

// ---------------- zero ----------------
__global__ void zero_k(float* p, int n) {
    int i = blockIdx.x * 256 + threadIdx.x;
    if (i < n) p[i] = 0.f;
}

// ---------------- split x into bf16 hi/lo ----------------
__global__ __launch_bounds__(256) void prep_x(const float* __restrict__ x,
                                              unsigned short* __restrict__ xhi,
                                              unsigned short* __restrict__ xlo) {
    int i = blockIdx.x * 256 + threadIdx.x;     // group of 4 floats
    if ((size_t)i * 4 >= (size_t)N_NODES * DIM) return;
    f32x4 v = *(const f32x4*)(x + (size_t)i * 4);
    u16x4 hi, lo;
#pragma unroll
    for (int j = 0; j < 4; ++j) {
        unsigned short hb = f2bf_rne(v[j]);
        float r = v[j] - bf2f(hb);
        hi[j] = hb;
        lo[j] = f2bf_rne(r);
    }
    *(u16x4*)(xhi + (size_t)i * 4) = hi;
    *(u16x4*)(xlo + (size_t)i * 4) = lo;
}

// ---------------- transpose + split W[2] -> Wt (col-major K-contig) ----------------
__global__ __launch_bounds__(256) void prep_w(const float* __restrict__ W2,
                                              unsigned short* __restrict__ wthi,
                                              unsigned short* __restrict__ wtlo) {
    __shared__ float tile[64][65];
    int bc = blockIdx.x;      // output-col tile
    int bk = blockIdx.y;      // k tile
    int t = threadIdx.x;
    int tj = t & 63, ti = t >> 6;
#pragma unroll
    for (int u = 0; u < 16; ++u) {
        int r = u * 4 + ti;   // k-local
        tile[r][tj] = W2[(size_t)(bk * 64 + r) * DIM + bc * 64 + tj];
    }
    __syncthreads();
#pragma unroll
    for (int u = 0; u < 16; ++u) {
        int cr = u * 4 + ti;  // c-local
        float v = tile[tj][cr];   // = W2[bk*64+tj][bc*64+cr]
        unsigned short hb = f2bf_rne(v);
        float rres = v - bf2f(hb);
        size_t o = (size_t)(bc * 64 + cr) * DIM + bk * 64 + tj;
        wthi[o] = hb;
        wtlo[o] = f2bf_rne(rres);
    }
}

// ---------------- 3-term split-bf16 MFMA GEMM: h = x @ W2 ----------------
// x @ W ~= xhi@Whi + xhi@Wlo + xlo@Whi  (fp32 accumulate; |err| ~ 2^-16 rel)
#define BM 128
#define BN 128
#define BK 32
#define LDK 40   // padded LDS k-stride (bf16 units): row stride 80B -> 2-way bank alias (free, m136)

__global__ __launch_bounds__(256) void gemm3(const unsigned short* __restrict__ xhi,
                                             const unsigned short* __restrict__ xlo,
                                             const unsigned short* __restrict__ wthi,
                                             const unsigned short* __restrict__ wtlo,
                                             float* __restrict__ hout) {
    __shared__ short lds[4][BM * LDK];   // 0:Ahi 1:Alo 2:Bhi 3:Blo
    const int t = threadIdx.x;
    const int r0 = blockIdx.y * BM;
    const int c0 = blockIdx.x * BN;
    const int lane = t & 63, wid = t >> 6;
    const int wm = wid >> 1, wn = wid & 1;

    f32x4 acc[4][4];
#pragma unroll
    for (int mi = 0; mi < 4; ++mi)
#pragma unroll
        for (int ni = 0; ni < 4; ++ni) acc[mi][ni] = (f32x4){0.f, 0.f, 0.f, 0.f};

    const int rL = lane & 15;
    const int koff = (lane >> 4) * 8;

    for (int k0 = 0; k0 < DIM; k0 += BK) {
        __syncthreads();   // protect previous iteration's reads
        // stage 2048 16B segments: A(hi,lo) 1024 + B(hi,lo) 1024
#pragma unroll
        for (int u = 0; u < 8; ++u) {
            int idx = u * 256 + t;          // 0..2047
            int which = idx >> 9;           // 0..3
            int rem = idx & 511;
            int row = rem >> 2;             // 0..127
            int seg = rem & 3;
            const unsigned short* src;
            bool ok = true;
            if (which == 0)      { int gr = r0 + row; ok = gr < N_NODES; src = xhi + (size_t)gr * DIM + k0 + seg * 8; }
            else if (which == 1) { int gr = r0 + row; ok = gr < N_NODES; src = xlo + (size_t)gr * DIM + k0 + seg * 8; }
            else if (which == 2) { src = wthi + (size_t)(c0 + row) * DIM + k0 + seg * 8; }
            else                 { src = wtlo + (size_t)(c0 + row) * DIM + k0 + seg * 8; }
            bf16x8 v = {0,0,0,0,0,0,0,0};
            if (ok) v = *(const bf16x8*)src;
            *(bf16x8*)&lds[which][row * LDK + seg * 8] = v;
        }
        __syncthreads();

        bf16x8 ahi[4], alo[4], bhi[4], blo[4];
#pragma unroll
        for (int mi = 0; mi < 4; ++mi) {
            int row = wm * 64 + mi * 16 + rL;
            ahi[mi] = *(const bf16x8*)&lds[0][row * LDK + koff];
            alo[mi] = *(const bf16x8*)&lds[1][row * LDK + koff];
        }
#pragma unroll
        for (int ni = 0; ni < 4; ++ni) {
            int row = wn * 64 + ni * 16 + rL;
            bhi[ni] = *(const bf16x8*)&lds[2][row * LDK + koff];
            blo[ni] = *(const bf16x8*)&lds[3][row * LDK + koff];
        }
#pragma unroll
        for (int mi = 0; mi < 4; ++mi)
#pragma unroll
            for (int ni = 0; ni < 4; ++ni) {
                f32x4 c = acc[mi][ni];
                c = __builtin_amdgcn_mfma_f32_16x16x32_bf16(ahi[mi], bhi[ni], c, 0, 0, 0);
                c = __builtin_amdgcn_mfma_f32_16x16x32_bf16(ahi[mi], blo[ni], c, 0, 0, 0);
                c = __builtin_amdgcn_mfma_f32_16x16x32_bf16(alo[mi], bhi[ni], c, 0, 0, 0);
                acc[mi][ni] = c;
            }
    }

#pragma unroll
    for (int mi = 0; mi < 4; ++mi)
#pragma unroll
        for (int ni = 0; ni < 4; ++ni)
#pragma unroll
            for (int v = 0; v < 4; ++v) {
                int row = r0 + wm * 64 + mi * 16 + ((lane >> 4) << 2) + v;
                if (row < N_NODES) {
                    int col = c0 + wn * 64 + ni * 16 + (lane & 15);
                    hout[(size_t)row * DIM + col] = acc[mi][ni][v];
                }
            }
}

// ---------------- per-node attention logits es/ed ----------------
__global__ __launch_bounds__(256) void dots_k(const float* __restrict__ h,
                                              const float* __restrict__ asrc,
                                              const float* __restrict__ adst,
                                              float* __restrict__ es,
                                              float* __restrict__ ed) {
    int wid = threadIdx.x >> 6, lane = threadIdx.x & 63;
    int n = blockIdx.x * 4 + wid;
    if (n >= N_NODES) return;
    const float* hr = h + (size_t)n * DIM;
    f32x4 sa = {0.f, 0.f, 0.f, 0.f}, sd = {0.f, 0.f, 0.f, 0.f};
#pragma unroll
    for (int k = 0; k < 4; ++k)
#pragma unroll
        for (int j = 0; j < 4; ++j) {
            int col = k * 256 + j * 64 + lane;
            float v = hr[col];
            sa[k] += v * asrc[col];
            sd[k] += v * adst[col];
        }
#pragma unroll
    for (int d = 1; d < 64; d <<= 1) {
#pragma unroll
        for (int k = 0; k < 4; ++k) {
            sa[k] += __shfl_xor(sa[k], d);
            sd[k] += __shfl_xor(sd[k], d);
        }
    }
    if (lane == 0) {
        *(f32x4*)(es + (size_t)n * 4) = sa;
        *(f32x4*)(ed + (size_t)n * 4) = sd;
    }
}

// ---------------- CSR build ----------------
__global__ void init_counts(const int* __restrict__ batch, int* cnt, int* cursor, int* gcnt) {
    int n = blockIdx.x * 256 + threadIdx.x;
    if (n >= N_NODES) return;
    cnt[n] = 1;          // self loop
    cursor[n] = 0;
    atomicAdd(gcnt + batch[n], 1);
}

__global__ void edge_hist(const int* __restrict__ dst, int* cnt) {
    int e = blockIdx.x * 256 + threadIdx.x;
    if (e >= N_EDGES) return;
    atomicAdd(cnt + dst[e], 1);
}

__global__ __launch_bounds__(1024) void scan_k(const int* __restrict__ cnt, int* __restrict__ off) {
    __shared__ int s[1024];
    int t = threadIdx.x;
    int running = 0;
    for (int c0 = 0; c0 < N_NODES; c0 += 1024) {
        int i = c0 + t;
        int v = (i < N_NODES) ? cnt[i] : 0;
        s[t] = v;
        __syncthreads();
        for (int d = 1; d < 1024; d <<= 1) {
            int x = (t >= d) ? s[t - d] : 0;
            __syncthreads();
            s[t] += x;
            __syncthreads();
        }
        if (i < N_NODES) off[i] = running + s[t] - v;
        int tot = s[1023];
        __syncthreads();
        running += tot;
    }
}

__global__ void bucket_k(const int* __restrict__ src, const int* __restrict__ dst,
                         const int* __restrict__ off, int* cursor, int* bucket) {
    int e = blockIdx.x * 256 + threadIdx.x;
    if (e >= ETOT) return;
    int d = (e < N_EDGES) ? dst[e] : (e - N_EDGES);
    int pos = atomicAdd(cursor + d, 1);
    bucket[off[d] + pos] = e;
}

// ---------------- fused softmax + aggregate + bias + relu + graph-pool ----------------
#define HCAP 192
__global__ __launch_bounds__(256) void aggregate_k(const float* __restrict__ h,
                                                   const float* __restrict__ es,
                                                   const float* __restrict__ ed,
                                                   const int* __restrict__ src,
                                                   const int* __restrict__ cnt,
                                                   const int* __restrict__ off,
                                                   const int* __restrict__ bucket,
                                                   const int* __restrict__ batch,
                                                   const float* __restrict__ b2,
                                                   float* __restrict__ pooled) {
    int n = blockIdx.x, t = threadIdx.x;
    int deg = cnt[n], base = off[n];
    f32x4 edn = *(const f32x4*)(ed + (size_t)n * 4);
    __shared__ int  s_src[HCAP];
    __shared__ f32x4 s_e[HCAP];
    __shared__ f32x4 wred[4];

    // phase 1: edge scores + per-head max (strided across threads)
    f32x4 m4 = {-3e38f, -3e38f, -3e38f, -3e38f};
    for (int i = t; i < deg; i += 256) {
        int eid = bucket[base + i];
        int s = (eid < N_EDGES) ? src[eid] : (eid - N_EDGES);
        f32x4 e4 = *(const f32x4*)(es + (size_t)s * 4);
        e4.x = lrelu(e4.x + edn.x); e4.y = lrelu(e4.y + edn.y);
        e4.z = lrelu(e4.z + edn.z); e4.w = lrelu(e4.w + edn.w);
        if (i < HCAP) { s_src[i] = s; s_e[i] = e4; }
        m4.x = fmaxf(m4.x, e4.x); m4.y = fmaxf(m4.y, e4.y);
        m4.z = fmaxf(m4.z, e4.z); m4.w = fmaxf(m4.w, e4.w);
    }
#pragma unroll
    for (int d = 1; d < 64; d <<= 1) {
        m4.x = fmaxf(m4.x, __shfl_xor(m4.x, d));
        m4.y = fmaxf(m4.y, __shfl_xor(m4.y, d));
        m4.z = fmaxf(m4.z, __shfl_xor(m4.z, d));
        m4.w = fmaxf(m4.w, __shfl_xor(m4.w, d));
    }
    if ((t & 63) == 0) wred[t >> 6] = m4;
    __syncthreads();
    f32x4 mm = wred[0];
#pragma unroll
    for (int w = 1; w < 4; ++w) {
        mm.x = fmaxf(mm.x, wred[w].x); mm.y = fmaxf(mm.y, wred[w].y);
        mm.z = fmaxf(mm.z, wred[w].z); mm.w = fmaxf(mm.w, wred[w].w);
    }
    int hd = t >> 6;
    float mh = hd == 0 ? mm.x : hd == 1 ? mm.y : hd == 2 ? mm.z : mm.w;

    // phase 2: weighted accumulate (thread t owns cols [t*4, t*4+4))
    f32x4 acc = {0.f, 0.f, 0.f, 0.f};
    float sump = 0.f;
    for (int i = 0; i < deg; ++i) {
        int s;
        f32x4 e4;
        if (i < HCAP) { s = s_src[i]; e4 = s_e[i]; }
        else {
            int eid = bucket[base + i];
            s = (eid < N_EDGES) ? src[eid] : (eid - N_EDGES);
            e4 = *(const f32x4*)(es + (size_t)s * 4);
            e4.x = lrelu(e4.x + edn.x); e4.y = lrelu(e4.y + edn.y);
            e4.z = lrelu(e4.z + edn.z); e4.w = lrelu(e4.w + edn.w);
        }
        float eh = hd == 0 ? e4.x : hd == 1 ? e4.y : hd == 2 ? e4.z : e4.w;
        float p = expf(eh - mh);
        sump += p;
        f32x4 hv = *(const f32x4*)(h + (size_t)s * DIM + t * 4);
        acc += p * hv;
    }
    float inv = 1.0f / (sump + 1e-16f);
    f32x4 bb = *(const f32x4*)(b2 + t * 4);
    f32x4 r = acc * inv + bb;
    r.x = fmaxf(r.x, 0.f); r.y = fmaxf(r.y, 0.f);
    r.z = fmaxf(r.z, 0.f); r.w = fmaxf(r.w, 0.f);
    int bg = batch[n];
    float* pp = pooled + (size_t)bg * DIM + t * 4;
    atomicAdd(pp + 0, r.x);
    atomicAdd(pp + 1, r.y);
    atomicAdd(pp + 2, r.z);
    atomicAdd(pp + 3, r.w);
}

// ---------------- final: (pooled/cnt) @ Wr + br ----------------
__global__ __launch_bounds__(256) void final_k(const float* __restrict__ pooled,
                                               const int* __restrict__ gcnt,
                                               const float* __restrict__ Wr,
                                               const float* __restrict__ br,
                                               float* __restrict__ out) {
    int g = blockIdx.x, t = threadIdx.x;
    float s0 = 0.f, s1 = 0.f;
    for (int d = t; d < DIM; d += 256) {
        float v = pooled[(size_t)g * DIM + d];
        s0 += v * Wr[d * 2];
        s1 += v * Wr[d * 2 + 1];
    }
    __shared__ float r0[256], r1[256];
    r0[t] = s0; r1[t] = s1;
    __syncthreads();
    for (int st = 128; st > 0; st >>= 1) {
        if (t < st) { r0[t] += r0[t + st]; r1[t] += r1[t + st]; }
        __syncthreads();
    }
    if (t == 0) {
        float c = fmaxf((float)gcnt[g], 1.f);
        out[g * 2 + 0] = r0[0] / c + br[0];
        out[g * 2 + 1] = r1[0] / c + br[1];
    }
}

// ---------------- launch ----------------
extern "C" void kernel_launch(void* const* d_in, const int* in_sizes, int n_in,
                              void* d_out, int out_size, void* d_ws, size_t ws_size,
                              hipStream_t stream) {
    (void)in_sizes; (void)n_in; (void)out_size;
    const float* x     = (const float*)d_in[0];
    const int*   ei    = (const int*)d_in[1];
    const int*   batch = (const int*)d_in[2];
    const float* W     = (const float*)d_in[3];
    const float* a_src = (const float*)d_in[4];
    const float* a_dst = (const float*)d_in[5];
    const float* b     = (const float*)d_in[6];
    const float* Wr    = (const float*)d_in[7];
    const float* br    = (const float*)d_in[8];

    // Reference: h = relu(gat(x, W[i])) for i in 0..2, but each block reads the
    // ORIGINAL x -> only block i=2 affects the output. Blocks 0,1 are dead code.
    const float* W2    = W + (size_t)2 * DIM * DIM;
    const float* asrc2 = a_src + 2 * NHEAD * DHEAD;
    const float* adst2 = a_dst + 2 * NHEAD * DHEAD;
    const float* b2    = b + 2 * DIM;
    const int* srcI = ei;
    const int* dstI = ei + N_EDGES;

    char* wsp = (char*)d_ws;
    size_t o = 0;
    auto alloc = [&](size_t bytes) -> char* {
        char* p = wsp + o;
        o = (o + bytes + 255) & ~(size_t)255;
        return p;
    };
    unsigned short* xhi  = (unsigned short*)alloc((size_t)N_NODES * DIM * 2);
    unsigned short* xlo  = (unsigned short*)alloc((size_t)N_NODES * DIM * 2);
    unsigned short* wthi = (unsigned short*)alloc((size_t)DIM * DIM * 2);
    unsigned short* wtlo = (unsigned short*)alloc((size_t)DIM * DIM * 2);
    float* h    = (float*)alloc((size_t)N_NODES * DIM * 4);
    float* es   = (float*)alloc((size_t)N_NODES * 4 * 4);
    float* ed   = (float*)alloc((size_t)N_NODES * 4 * 4);
    int*   cnt  = (int*)alloc((size_t)N_NODES * 4);
    int*   offs = (int*)alloc((size_t)N_NODES * 4);
    int*   curs = (int*)alloc((size_t)N_NODES * 4);
    int*   bkt  = (int*)alloc((size_t)ETOT * 4);
    float* pooled = (float*)alloc((size_t)NGRAPH * DIM * 4);   // pooled(256KiB, 256-aligned) then gcnt contiguous
    int*   gcnt   = (int*)alloc(256);
    (void)ws_size;

    const int ZN = NGRAPH * DIM + 64;   // zero pooled + gcnt in one shot (contiguous)
    zero_k<<<(ZN + 255) / 256, 256, 0, stream>>>(pooled, ZN);

    prep_x<<<(N_NODES * DIM / 4 + 255) / 256, 256, 0, stream>>>(x, xhi, xlo);
    prep_w<<<dim3(16, 16), 256, 0, stream>>>(W2, wthi, wtlo);
    gemm3<<<dim3(DIM / BN, (N_NODES + BM - 1) / BM), 256, 0, stream>>>(xhi, xlo, wthi, wtlo, h);
    dots_k<<<(N_NODES + 3) / 4, 256, 0, stream>>>(h, asrc2, adst2, es, ed);

    init_counts<<<(N_NODES + 255) / 256, 256, 0, stream>>>(batch, cnt, curs, gcnt);
    edge_hist<<<(N_EDGES + 255) / 256, 256, 0, stream>>>(dstI, cnt);
    scan_k<<<1, 1024, 0, stream>>>(cnt, offs);
    bucket_k<<<(ETOT + 255) / 256, 256, 0, stream>>>(srcI, dstI, offs, curs, bkt);

    aggregate_k<<<N_NODES, 256, 0, stream>>>(h, es, ed, srcI, cnt, offs, bkt, batch, b2, pooled);
    final_k<<<NGRAPH, 256, 0, stream>>>(pooled, gcnt, Wr, br, (float*)d_out);
}

// Round 5
// 400.281 us; speedup vs baseline: 1.1952x; 1.1952x over previous
//
#include <hip/hip_runtime.h>
#include <hip/hip_bf16.h>

// Problem constants (fixed by the reference)
#define N_NODES 10000
#define N_EDGES 160000
#define ETOT    (N_NODES + N_EDGES)
#define DIM     1024
#define NHEAD   4
#define DHEAD   256
#define NGRAPH  64
#define NEG_SLOPE 0.2f

typedef short  bf16x8 __attribute__((ext_vector_type(8)));
typedef float  f32x4  __attribute__((ext_vector_type(4)));
typedef unsigned short u16x4 __attribute__((ext_vector_type(4)));
typedef unsigned short u16x8 __attribute__((ext_vector_type(8)));

__device__ __forceinline__ unsigned short f2bf_rne(float v) {
    unsigned u = __builtin_bit_cast(unsigned, v);
    return (unsigned short)((u + 0x7fffu + ((u >> 16) & 1u)) >> 16);
}
__device__ __forceinline__ float bf2f(unsigned short b) {
    return __builtin_bit_cast(float, (unsigned)b << 16);
}
__device__ __forceinline__ float lrelu(float x) { return x > 0.f ? x : NEG_SLOPE * x; }

// ---------------- split x into bf16 hi/lo ----------------
__global__ __launch_bounds__(256) void prep_x(const float* __restrict__ x,
                                              unsigned short* __restrict__ xhi,
                                              unsigned short* __restrict__ xlo) {
    int i = blockIdx.x * 256 + threadIdx.x;     // group of 4 floats
    if ((size_t)i * 4 >= (size_t)N_NODES * DIM) return;
    f32x4 v = *(const f32x4*)(x + (size_t)i * 4);
    u16x4 hi, lo;
#pragma unroll
    for (int j = 0; j < 4; ++j) {
        unsigned short hb = f2bf_rne(v[j]);
        float r = v[j] - bf2f(hb);
        hi[j] = hb;
        lo[j] = f2bf_rne(r);
    }
    *(u16x4*)(xhi + (size_t)i * 4) = hi;
    *(u16x4*)(xlo + (size_t)i * 4) = lo;
}

// ---------------- transpose + split W[2] -> Wt (col-major K-contig) ----------------
__global__ __launch_bounds__(256) void prep_w(const float* __restrict__ W2,
                                              unsigned short* __restrict__ wthi,
                                              unsigned short* __restrict__ wtlo) {
    __shared__ float tile[64][65];
    int bc = blockIdx.x;      // output-col tile
    int bk = blockIdx.y;      // k tile
    int t = threadIdx.x;
    int tj = t & 63, ti = t >> 6;
#pragma unroll
    for (int u = 0; u < 16; ++u) {
        int r = u * 4 + ti;   // k-local
        tile[r][tj] = W2[(size_t)(bk * 64 + r) * DIM + bc * 64 + tj];
    }
    __syncthreads();
#pragma unroll
    for (int u = 0; u < 16; ++u) {
        int cr = u * 4 + ti;  // c-local
        float v = tile[tj][cr];   // = W2[bk*64+tj][bc*64+cr]
        unsigned short hb = f2bf_rne(v);
        float rres = v - bf2f(hb);
        size_t o = (size_t)(bc * 64 + cr) * DIM + bk * 64 + tj;
        wthi[o] = hb;
        wtlo[o] = f2bf_rne(rres);
    }
}

// ---------------- 3-term split-bf16 MFMA GEMM: h = x @ W2 (bf16 output) ----------------
// x @ W ~= xhi@Whi + xhi@Wlo + xlo@Whi  (fp32 accumulate)
// m97 structure: global_load_lds width-16 staging, linear LDS (wave's fragment
// reads cover a contiguous 1 KB -> conflict-free, no padding needed).
#define BM 128
#define BN 128
#define BK 32

__global__ __launch_bounds__(256) void gemm3(const unsigned short* __restrict__ xhi,
                                             const unsigned short* __restrict__ xlo,
                                             const unsigned short* __restrict__ wthi,
                                             const unsigned short* __restrict__ wtlo,
                                             unsigned short* __restrict__ hb) {
    __shared__ short lds[4][BM * BK];   // 0:Ahi 1:Alo 2:Bhi 3:Blo — 8 KB each
    const int t = threadIdx.x;
    const int r0 = blockIdx.y * BM;
    const int c0 = blockIdx.x * BN;
    const int lane = t & 63, wid = t >> 6;
    const int wm = wid >> 1, wn = wid & 1;

    // each wave stages its own buffer: wave 0:Ahi 1:Alo 2:Bhi 3:Blo
    const unsigned short* const srcs[4] = {xhi, xlo, wthi, wtlo};
    const unsigned short* wbase = srcs[wid];
    const int rowb = (wid < 2) ? r0 : c0;
    // OOB A-rows (r0+row >= N_NODES) read garbage inside ws; those acc lanes are
    // never stored (row<N_NODES guard). 0xAA poison is a tiny denormal, no NaN.

    f32x4 acc[4][4];
#pragma unroll
    for (int mi = 0; mi < 4; ++mi)
#pragma unroll
        for (int ni = 0; ni < 4; ++ni) acc[mi][ni] = (f32x4){0.f, 0.f, 0.f, 0.f};

    const int rL = lane & 15;
    const int koff = (lane >> 4) * 8;   // element offset into K (8 bf16 = 16 B)

    for (int k0 = 0; k0 < DIM; k0 += BK) {
        __syncthreads();   // previous iteration's fragment reads done before overwrite
#pragma unroll
        for (int j = 0; j < 8; ++j) {
            // chunk j: rows j*16 + (lane>>2), 4 segments of 16 B per row
            const unsigned short* g = wbase
                + (size_t)(rowb + j * 16 + (lane >> 2)) * DIM + k0 + (lane & 3) * 8;
            __builtin_amdgcn_global_load_lds(
                (const __attribute__((address_space(1))) unsigned int*)g,
                (__attribute__((address_space(3))) unsigned int*)&lds[wid][j * 512],
                16, 0, 0);
        }
        __syncthreads();   // compiler drains vmcnt before barrier

        bf16x8 ahi[4], alo[4], bhi[4], blo[4];
#pragma unroll
        for (int mi = 0; mi < 4; ++mi) {
            int row = wm * 64 + mi * 16 + rL;
            ahi[mi] = *(const bf16x8*)&lds[0][row * BK + koff];
            alo[mi] = *(const bf16x8*)&lds[1][row * BK + koff];
        }
#pragma unroll
        for (int ni = 0; ni < 4; ++ni) {
            int row = wn * 64 + ni * 16 + rL;
            bhi[ni] = *(const bf16x8*)&lds[2][row * BK + koff];
            blo[ni] = *(const bf16x8*)&lds[3][row * BK + koff];
        }
#pragma unroll
        for (int mi = 0; mi < 4; ++mi)
#pragma unroll
            for (int ni = 0; ni < 4; ++ni) {
                f32x4 c = acc[mi][ni];
                c = __builtin_amdgcn_mfma_f32_16x16x32_bf16(ahi[mi], bhi[ni], c, 0, 0, 0);
                c = __builtin_amdgcn_mfma_f32_16x16x32_bf16(ahi[mi], blo[ni], c, 0, 0, 0);
                c = __builtin_amdgcn_mfma_f32_16x16x32_bf16(alo[mi], bhi[ni], c, 0, 0, 0);
                acc[mi][ni] = c;
            }
    }

    // epilogue: bf16 store (C/D map: col=lane&15, row=(lane>>4)*4+v  [m89/m91])
#pragma unroll
    for (int mi = 0; mi < 4; ++mi)
#pragma unroll
        for (int ni = 0; ni < 4; ++ni)
#pragma unroll
            for (int v = 0; v < 4; ++v) {
                int row = r0 + wm * 64 + mi * 16 + ((lane >> 4) << 2) + v;
                if (row < N_NODES) {
                    int col = c0 + wn * 64 + ni * 16 + (lane & 15);
                    hb[(size_t)row * DIM + col] = f2bf_rne(acc[mi][ni][v]);
                }
            }
}

// ---------------- per-node attention logits es/ed (bf16 h, vectorized) ----------------
__global__ __launch_bounds__(256) void dots_k(const unsigned short* __restrict__ hb,
                                              const float* __restrict__ asrc,
                                              const float* __restrict__ adst,
                                              float* __restrict__ es,
                                              float* __restrict__ ed) {
    int wid = threadIdx.x >> 6, lane = threadIdx.x & 63;
    int n = blockIdx.x * 4 + wid;
    if (n >= N_NODES) return;
    // lane owns elements [lane*16, lane*16+16) -> all within head lane>>4
    const unsigned short* hr = hb + (size_t)n * DIM + lane * 16;
    u16x8 a = *(const u16x8*)hr;
    u16x8 b8 = *(const u16x8*)(hr + 8);
    const float* ap = asrc + lane * 16;
    const float* dp = adst + lane * 16;
    float sa = 0.f, sd = 0.f;
#pragma unroll
    for (int j = 0; j < 8; ++j) {
        float v = bf2f(a[j]);
        sa += v * ap[j];
        sd += v * dp[j];
    }
#pragma unroll
    for (int j = 0; j < 8; ++j) {
        float v = bf2f(b8[j]);
        sa += v * ap[8 + j];
        sd += v * dp[8 + j];
    }
#pragma unroll
    for (int d = 1; d < 16; d <<= 1) {
        sa += __shfl_xor(sa, d);
        sd += __shfl_xor(sd, d);
    }
    if ((lane & 15) == 0) {
        int head = lane >> 4;
        es[(size_t)n * 4 + head] = sa;
        ed[(size_t)n * 4 + head] = sd;
    }
}

// ---------------- per-graph init ----------------
__global__ void init_misc(int* gcnt, int* gbeg, int* gend) {
    int t = threadIdx.x;
    if (t < NGRAPH) { gcnt[t] = 0; gbeg[t] = 0x7fffffff; gend[t] = -1; }
}

// ---------------- CSR build ----------------
__global__ void init_counts(const int* __restrict__ batch, int* cnt, int* cursor,
                            int* gcnt, int* gbeg, int* gend) {
    int n = blockIdx.x * 256 + threadIdx.x;
    if (n >= N_NODES) return;
    cnt[n] = 1;          // self loop
    cursor[n] = 0;
    int b = batch[n];
    atomicAdd(gcnt + b, 1);
    atomicMin(gbeg + b, n);
    atomicMax(gend + b, n);
}

__global__ void edge_hist(const int* __restrict__ dst, int* cnt) {
    int e = blockIdx.x * 256 + threadIdx.x;
    if (e >= N_EDGES) return;
    atomicAdd(cnt + dst[e], 1);
}

// shfl-based scan (wave-level, few barriers)
__global__ __launch_bounds__(1024) void scan_k(const int* __restrict__ cnt, int* __restrict__ off) {
    __shared__ int wsh[16];
    __shared__ int tot_s;
    int t = threadIdx.x, lane = t & 63, wv = t >> 6;
    int running = 0;
    for (int c0 = 0; c0 < N_NODES; c0 += 1024) {
        int i = c0 + t;
        int v = (i < N_NODES) ? cnt[i] : 0;
        int s = v;
#pragma unroll
        for (int d = 1; d < 64; d <<= 1) {
            int y = __shfl_up(s, d);
            if (lane >= d) s += y;
        }
        if (lane == 63) wsh[wv] = s;
        __syncthreads();
        if (wv == 0) {
            int wsv = (lane < 16) ? wsh[lane] : 0;
            int e = wsv;
#pragma unroll
            for (int d = 1; d < 16; d <<= 1) {
                int y = __shfl_up(e, d);
                if (lane >= d) e += y;
            }
            if (lane < 16) wsh[lane] = e - wsv;   // exclusive wave prefix
            if (lane == 15) tot_s = e;            // chunk total
        }
        __syncthreads();
        if (i < N_NODES) off[i] = running + wsh[wv] + s - v;
        running += tot_s;
    }
}

__global__ void bucket_k(const int* __restrict__ src, const int* __restrict__ dst,
                         const int* __restrict__ off, int* cursor, int* bucket) {
    int e = blockIdx.x * 256 + threadIdx.x;
    if (e >= ETOT) return;
    int d = (e < N_EDGES) ? dst[e] : (e - N_EDGES);
    int pos = atomicAdd(cursor + d, 1);
    bucket[off[d] + pos] = e;
}

// ---------------- fused softmax + aggregate + bias + relu -> out[n] ----------------
#define HCAP 192
__global__ __launch_bounds__(256) void aggregate_k(const unsigned short* __restrict__ hb,
                                                   const float* __restrict__ es,
                                                   const float* __restrict__ ed,
                                                   const int* __restrict__ src,
                                                   const int* __restrict__ cnt,
                                                   const int* __restrict__ off,
                                                   const int* __restrict__ bucket,
                                                   const float* __restrict__ b2,
                                                   float* __restrict__ out) {
    int n = blockIdx.x, t = threadIdx.x;
    int deg = cnt[n], base = off[n];
    f32x4 edn = *(const f32x4*)(ed + (size_t)n * 4);
    __shared__ int  s_src[HCAP];
    __shared__ f32x4 s_e[HCAP];
    __shared__ f32x4 wred[4];

    // phase 1: edge scores + per-head max
    f32x4 m4 = {-3e38f, -3e38f, -3e38f, -3e38f};
    for (int i = t; i < deg; i += 256) {
        int eid = bucket[base + i];
        int s = (eid < N_EDGES) ? src[eid] : (eid - N_EDGES);
        f32x4 e4 = *(const f32x4*)(es + (size_t)s * 4);
        e4.x = lrelu(e4.x + edn.x); e4.y = lrelu(e4.y + edn.y);
        e4.z = lrelu(e4.z + edn.z); e4.w = lrelu(e4.w + edn.w);
        if (i < HCAP) { s_src[i] = s; s_e[i] = e4; }
        m4.x = fmaxf(m4.x, e4.x); m4.y = fmaxf(m4.y, e4.y);
        m4.z = fmaxf(m4.z, e4.z); m4.w = fmaxf(m4.w, e4.w);
    }
#pragma unroll
    for (int d = 1; d < 64; d <<= 1) {
        m4.x = fmaxf(m4.x, __shfl_xor(m4.x, d));
        m4.y = fmaxf(m4.y, __shfl_xor(m4.y, d));
        m4.z = fmaxf(m4.z, __shfl_xor(m4.z, d));
        m4.w = fmaxf(m4.w, __shfl_xor(m4.w, d));
    }
    if ((t & 63) == 0) wred[t >> 6] = m4;
    __syncthreads();
    f32x4 mm = wred[0];
#pragma unroll
    for (int w = 1; w < 4; ++w) {
        mm.x = fmaxf(mm.x, wred[w].x); mm.y = fmaxf(mm.y, wred[w].y);
        mm.z = fmaxf(mm.z, wred[w].z); mm.w = fmaxf(mm.w, wred[w].w);
    }
    int hd = t >> 6;
    float mh = hd == 0 ? mm.x : hd == 1 ? mm.y : hd == 2 ? mm.z : mm.w;

    // phase 2: weighted accumulate over bf16 h rows (thread t owns cols [t*4, t*4+4))
    f32x4 acc = {0.f, 0.f, 0.f, 0.f};
    float sump = 0.f;
    for (int i = 0; i < deg; ++i) {
        int s;
        f32x4 e4;
        if (i < HCAP) { s = s_src[i]; e4 = s_e[i]; }
        else {
            int eid = bucket[base + i];
            s = (eid < N_EDGES) ? src[eid] : (eid - N_EDGES);
            e4 = *(const f32x4*)(es + (size_t)s * 4);
            e4.x = lrelu(e4.x + edn.x); e4.y = lrelu(e4.y + edn.y);
            e4.z = lrelu(e4.z + edn.z); e4.w = lrelu(e4.w + edn.w);
        }
        float eh = hd == 0 ? e4.x : hd == 1 ? e4.y : hd == 2 ? e4.z : e4.w;
        float p = expf(eh - mh);
        sump += p;
        u16x4 q = *(const u16x4*)(hb + (size_t)s * DIM + t * 4);
        f32x4 hv = {bf2f(q[0]), bf2f(q[1]), bf2f(q[2]), bf2f(q[3])};
        acc += p * hv;
    }
    float inv = 1.0f / (sump + 1e-16f);
    f32x4 bb = *(const f32x4*)(b2 + t * 4);
    f32x4 r = acc * inv + bb;
    r.x = fmaxf(r.x, 0.f); r.y = fmaxf(r.y, 0.f);
    r.z = fmaxf(r.z, 0.f); r.w = fmaxf(r.w, 0.f);
    *(f32x4*)(out + (size_t)n * DIM + t * 4) = r;   // plain coalesced store, no atomics
}

// ---------------- per-graph pooling (no atomics: batch is sorted) ----------------
__global__ __launch_bounds__(256) void pool_k(const float* __restrict__ out,
                                              const int* __restrict__ gbeg,
                                              const int* __restrict__ gend,
                                              float* __restrict__ pooled) {
    int g = blockIdx.x, c = blockIdx.y, t = threadIdx.x;
    int col = c * 256 + t;
    int b0 = gbeg[g], b1 = gend[g];
    float acc = 0.f;
    for (int n = b0; n <= b1; ++n) acc += out[(size_t)n * DIM + col];
    pooled[(size_t)g * DIM + col] = acc;   // sum; final_k divides by count
}

// ---------------- final: (pooled/cnt) @ Wr + br ----------------
__global__ __launch_bounds__(256) void final_k(const float* __restrict__ pooled,
                                               const int* __restrict__ gcnt,
                                               const float* __restrict__ Wr,
                                               const float* __restrict__ br,
                                               float* __restrict__ out) {
    int g = blockIdx.x, t = threadIdx.x;
    float s0 = 0.f, s1 = 0.f;
    for (int d = t; d < DIM; d += 256) {
        float v = pooled[(size_t)g * DIM + d];
        s0 += v * Wr[d * 2];
        s1 += v * Wr[d * 2 + 1];
    }
    __shared__ float r0[256], r1[256];
    r0[t] = s0; r1[t] = s1;
    __syncthreads();
    for (int st = 128; st > 0; st >>= 1) {
        if (t < st) { r0[t] += r0[t + st]; r1[t] += r1[t + st]; }
        __syncthreads();
    }
    if (t == 0) {
        float c = fmaxf((float)gcnt[g], 1.f);
        out[g * 2 + 0] = r0[0] / c + br[0];
        out[g * 2 + 1] = r1[0] / c + br[1];
    }
}

// ---------------- launch ----------------
extern "C" void kernel_launch(void* const* d_in, const int* in_sizes, int n_in,
                              void* d_out, int out_size, void* d_ws, size_t ws_size,
                              hipStream_t stream) {
    (void)in_sizes; (void)n_in; (void)out_size; (void)ws_size;
    const float* x     = (const float*)d_in[0];
    const int*   ei    = (const int*)d_in[1];
    const int*   batch = (const int*)d_in[2];
    const float* W     = (const float*)d_in[3];
    const float* a_src = (const float*)d_in[4];
    const float* a_dst = (const float*)d_in[5];
    const float* b     = (const float*)d_in[6];
    const float* Wr    = (const float*)d_in[7];
    const float* br    = (const float*)d_in[8];

    // Reference: each block reads the ORIGINAL x -> only block i=2 matters.
    const float* W2    = W + (size_t)2 * DIM * DIM;
    const float* asrc2 = a_src + 2 * NHEAD * DHEAD;
    const float* adst2 = a_dst + 2 * NHEAD * DHEAD;
    const float* b2    = b + 2 * DIM;
    const int* srcI = ei;
    const int* dstI = ei + N_EDGES;

    char* wsp = (char*)d_ws;
    size_t o = 0;
    auto alloc = [&](size_t bytes) -> char* {
        char* p = wsp + o;
        o = (o + bytes + 255) & ~(size_t)255;
        return p;
    };
    unsigned short* xhi  = (unsigned short*)alloc((size_t)N_NODES * DIM * 2);  // 20.48 MB
    unsigned short* xlo  = (unsigned short*)alloc((size_t)N_NODES * DIM * 2);  // 20.48 MB (contiguous after xhi)
    unsigned short* wthi = (unsigned short*)alloc((size_t)DIM * DIM * 2);
    unsigned short* wtlo = (unsigned short*)alloc((size_t)DIM * DIM * 2);
    unsigned short* hb   = (unsigned short*)alloc((size_t)N_NODES * DIM * 2);  // h in bf16
    float* es   = (float*)alloc((size_t)N_NODES * 4 * 4);
    float* ed   = (float*)alloc((size_t)N_NODES * 4 * 4);
    int*   cnt  = (int*)alloc((size_t)N_NODES * 4);
    int*   offs = (int*)alloc((size_t)N_NODES * 4);
    int*   curs = (int*)alloc((size_t)N_NODES * 4);
    int*   bkt  = (int*)alloc((size_t)ETOT * 4);
    float* pooled = (float*)alloc((size_t)NGRAPH * DIM * 4);
    int*   gcnt   = (int*)alloc(NGRAPH * 4);
    int*   gbeg   = (int*)alloc(NGRAPH * 4);
    int*   gend   = (int*)alloc(NGRAPH * 4);
    // out[n] (41 MB f32) aliases xhi+xlo — dead after gemm3. (xhi size is a
    // multiple of 256 so xlo is contiguous; combined = exactly N*DIM*4 bytes.)
    float* outn = (float*)xhi;

    init_misc<<<1, 64, 0, stream>>>(gcnt, gbeg, gend);
    prep_x<<<(N_NODES * DIM / 4 + 255) / 256, 256, 0, stream>>>(x, xhi, xlo);
    prep_w<<<dim3(16, 16), 256, 0, stream>>>(W2, wthi, wtlo);
    gemm3<<<dim3(DIM / BN, (N_NODES + BM - 1) / BM), 256, 0, stream>>>(xhi, xlo, wthi, wtlo, hb);
    dots_k<<<(N_NODES + 3) / 4, 256, 0, stream>>>(hb, asrc2, adst2, es, ed);

    init_counts<<<(N_NODES + 255) / 256, 256, 0, stream>>>(batch, cnt, curs, gcnt, gbeg, gend);
    edge_hist<<<(N_EDGES + 255) / 256, 256, 0, stream>>>(dstI, cnt);
    scan_k<<<1, 1024, 0, stream>>>(cnt, offs);
    bucket_k<<<(ETOT + 255) / 256, 256, 0, stream>>>(srcI, dstI, offs, curs, bkt);

    aggregate_k<<<N_NODES, 256, 0, stream>>>(hb, es, ed, srcI, cnt, offs, bkt, b2, outn);
    pool_k<<<dim3(NGRAPH, 4), 256, 0, stream>>>(outn, gbeg, gend, pooled);
    final_k<<<NGRAPH, 256, 0, stream>>>(pooled, gcnt, Wr, br, (float*)d_out);
}